// Round 12
// baseline (251.408 us; speedup 1.0000x reference)
//
#include <hip/hip_runtime.h>
#include <hip/hip_bf16.h>
#include <hip/hip_fp16.h>

#define D 64
#define K3E 4096
#define ECAP 6144   // slots per 256-node bucket (mean fill 4082, sigma 64 -> 32 sigma headroom)

// Edge word packing (requires N <= 65536, V <= 128 — true for this problem):
//   bits [0:15]  = src node
//   bits [16:22] = x[src]   (vocab id)
//   bits [23:30] = dst & 255 (node index within its 256-node bucket)
//
// Padded-bucket CSR: bucket b owns ebuf/col slots [b*ECAP, b*ECAP + fill_b).
// LESSONS (measured):
//  R6: per-node shuffle-GEMM fusion = 2x slower (latency-serial, 25% occ).
//  R2: guarded (skipped) loads lose to clamped loads — MLP beats issue-waste.
//  R9: csr_build/gather split neutral -> remaining cost is serial dispatches
//      + intermediate traffic.
//  R10 BUG (inf): gather phase covered 16/64 rows of the block tile; GEMM read
//      uninitialized LDS. FIX: each of the 16 waves loops 4 nodes (nt=w*4+i)
//      so all 64 Ht rows are written.

// ===== fused front-end: blocks [0,NG) compute embW = emb @ Wgcn (fp32);
//       blocks [NG,..) scatter edges into padded bucket regions. =====

__global__ __launch_bounds__(256) void embw_scatter_kernel(
    const float* __restrict__ emb, int nrows,
    const float* __restrict__ W1, float* __restrict__ embW, int NG,
    const int* __restrict__ src, const int* __restrict__ dst,
    const int* __restrict__ x,
    int* __restrict__ bucketFill, int* __restrict__ ebuf, int E)
{
    __shared__ union SM {
        struct { float At[64][68]; float Ws1[64][64]; } g;
        struct { int uu[K3E]; unsigned char bb[K3E]; int hist[256]; int resBase[256]; } s;
    } sm;
    int t = threadIdx.x;

    if ((int)blockIdx.x >= NG) {
        // ---- scatter half: one 4096-edge tile per block ----
        int bid = blockIdx.x - NG;
        int* uu = sm.s.uu;
        unsigned char* bb = sm.s.bb;
        int* hist = sm.s.hist;
        int* resBase = sm.s.resBase;
        hist[t] = 0;
        __syncthreads();
        int e0 = bid * K3E;
        int cnt = E - e0; if (cnt > K3E) cnt = K3E;
        for (int i = t; i < cnt; i += 256) {
            int e = e0 + i;
            int s = src[e];
            int d = dst[e];
            int xs = x[s];
            uu[i] = s | (xs << 16) | ((d & 255) << 23);
            int b = d >> 8;
            bb[i] = (unsigned char)b;
            atomicAdd(&hist[b], 1);
        }
        __syncthreads();
        int c = hist[t];
        if (c) resBase[t] = t * ECAP + atomicAdd(&bucketFill[t], c);
        __syncthreads();
        hist[t] = 0;
        __syncthreads();
        for (int i = t; i < cnt; i += 256) {
            int b = bb[i];
            int r = atomicAdd(&hist[b], 1);
            int idx = resBase[b] + r;
            if (idx < (b + 1) * ECAP) ebuf[idx] = uu[i];   // overflow guard (never hit at 32 sigma)
        }
        return;
    }

    // ---- embW GEMM half (fp32, V rows) ----
    {
        const float4* w1v = (const float4*)W1;
        float4* s1 = (float4*)&sm.g.Ws1[0][0];
        for (int i = t; i < 1024; i += 256) s1[i] = w1v[i];
    }
    int r0 = blockIdx.x * 64;
    for (int i = t; i < 1024; i += 256) {
        int r = i >> 4, c4 = i & 15;
        int gr = r0 + r; if (gr >= nrows) gr = nrows - 1;
        float4 v = ((const float4*)(emb + (size_t)gr * D))[c4];
        float* dp = &sm.g.At[r][c4 * 4];
        dp[0] = v.x; dp[1] = v.y; dp[2] = v.z; dp[3] = v.w;
    }
    __syncthreads();

    int cg = t & 15;
    int rg = t >> 4;
    float acc1[4][4] = {{0.f}};

    for (int k0 = 0; k0 < 64; k0 += 4) {
        float4 a[4], w1[4];
#pragma unroll
        for (int i = 0; i < 4; ++i) a[i] = *(const float4*)&sm.g.At[4 * rg + i][k0];
#pragma unroll
        for (int j = 0; j < 4; ++j) w1[j] = *(const float4*)&sm.g.Ws1[k0 + j][cg * 4];
#pragma unroll
        for (int i = 0; i < 4; ++i) {
            float av[4] = {a[i].x, a[i].y, a[i].z, a[i].w};
#pragma unroll
            for (int kk = 0; kk < 4; ++kk) {
                acc1[i][0] += av[kk] * w1[kk].x;
                acc1[i][1] += av[kk] * w1[kk].y;
                acc1[i][2] += av[kk] * w1[kk].z;
                acc1[i][3] += av[kk] * w1[kk].w;
            }
        }
    }
#pragma unroll
    for (int i = 0; i < 4; ++i) {
        int gr = r0 + 4 * rg + i;
        if (gr < nrows) {
            float4 o;
            o.x = acc1[i][0]; o.y = acc1[i][1]; o.z = acc1[i][2]; o.w = acc1[i][3];
            ((float4*)(embW + (size_t)gr * D))[cg] = o;
        }
    }
}

// ===== per-bucket exact CSR build (LDS 27 KB) =====

__global__ __launch_bounds__(1024) void csr_build_kernel(
    const int* __restrict__ ebuf, const int* __restrict__ bucketFill,
    int* __restrict__ rowbeg, int* __restrict__ rowend, int* __restrict__ col,
    int N)
{
    __shared__ int eLds[ECAP];       // 24 KB
    __shared__ int hist[256];        // 1 KB
    __shared__ int sc[256];          // 1 KB
    int b = blockIdx.x, t = threadIdx.x;
    int base = b * ECAP;
    int m = bucketFill[b]; if (m > ECAP) m = ECAP;

    if (t < 256) hist[t] = 0;
    __syncthreads();

    for (int i = t; i < m; i += 1024) {
        int u = ebuf[base + i];
        eLds[i] = u;
        atomicAdd(&hist[(u >> 23) & 255], 1);
    }
    __syncthreads();

    int v = (t < 256) ? hist[t] : 0;
    if (t < 256) sc[t] = v;
    __syncthreads();
    for (int off = 1; off < 256; off <<= 1) {
        int w = (t >= off && t < 256) ? sc[t - off] : 0;
        __syncthreads();
        if (t < 256) sc[t] += w;
        __syncthreads();
    }
    if (t < 256) {
        int excl = sc[t] - v;
        int node = (b << 8) + t;
        if (node < N) {
            rowbeg[node] = base + excl;
            rowend[node] = base + sc[t];
        }
        hist[t] = excl;   // running local cursor
    }
    __syncthreads();

    for (int i = t; i < m; i += 1024) {
        int u = eLds[i];
        int dl = (u >> 23) & 255;
        int r = atomicAdd(&hist[dl], 1);
        col[base + r] = u;
    }
}

// ===== fused gather+GEMM kernels =====
// Structure (shared by all three): 64 nodes/block, 16 waves; each wave
// gathers 4 nodes (nt = w*4+i, proven clamped-unroll shape, full MLP),
// writing fp32 rows into LDS Ht. Then a block-tiled GEMM (gemm64h access
// pattern remapped to 1024 threads: thread = (row, colgroup)).

// --- kernel 1: h1 = relu(sum_nb embW[x[u]]);  Ah = h1@Wsl; B = h1@Wsr ---

__global__ __launch_bounds__(1024) void gcn_gemm1_kernel(
    const int* __restrict__ rowbeg, const int* __restrict__ rowend,
    const int* __restrict__ col,
    const float* __restrict__ embW,
    const float* __restrict__ Wsl, const float* __restrict__ Wsr,
    __half* __restrict__ h1, __half* __restrict__ Ah, __half* __restrict__ Bm,
    int N)
{
    __shared__ float Ht[64][68];     // 17.4 KB
    __shared__ float Ws1[64][64];    // 16 KB
    __shared__ float Ws2[64][64];    // 16 KB
    int t = threadIdx.x;
    {
        ((float4*)&Ws1[0][0])[t] = ((const float4*)Wsl)[t];
        ((float4*)&Ws2[0][0])[t] = ((const float4*)Wsr)[t];
    }
    int w = t >> 6, lane = t & 63;
    int grp = lane >> 4, li = lane & 15;
    int r0 = blockIdx.x * 64;

#pragma unroll
    for (int i = 0; i < 4; ++i) {
        int nt = w * 4 + i;
        int v = r0 + nt;
        if (v < N) {
            int beg = rowbeg[v], end = rowend[v];
            float a0 = 0.f, a1 = 0.f, a2 = 0.f, a3 = 0.f;
            for (int e0 = beg; e0 < end; e0 += 32) {
#pragma unroll
                for (int j = 0; j < 8; ++j) {
                    int e = e0 + 4 * j + grp;
                    float m = (e < end) ? 1.f : 0.f;
                    int ec = (e < end) ? e : (end - 1);
                    int xu = (col[ec] >> 16) & 0x7F;
                    float4 f = *((const float4*)(embW + (size_t)xu * D) + li);
                    a0 += m * f.x; a1 += m * f.y; a2 += m * f.z; a3 += m * f.w;
                }
            }
            a0 += __shfl_xor(a0, 16); a0 += __shfl_xor(a0, 32);
            a1 += __shfl_xor(a1, 16); a1 += __shfl_xor(a1, 32);
            a2 += __shfl_xor(a2, 16); a2 += __shfl_xor(a2, 32);
            a3 += __shfl_xor(a3, 16); a3 += __shfl_xor(a3, 32);
            if (grp == 0) {
                a0 = fmaxf(a0, 0.f); a1 = fmaxf(a1, 0.f);
                a2 = fmaxf(a2, 0.f); a3 = fmaxf(a3, 0.f);
                *(float4*)&Ht[nt][li * 4] = make_float4(a0, a1, a2, a3);
                float2 oh;
                *(__half2*)&oh.x = __floats2half2_rn(a0, a1);
                *(__half2*)&oh.y = __floats2half2_rn(a2, a3);
                ((float2*)(h1 + (size_t)v * D))[li] = oh;
            }
        } else if (grp == 0) {
            *(float4*)&Ht[nt][li * 4] = make_float4(0.f, 0.f, 0.f, 0.f);
        }
    }
    __syncthreads();

    // GEMM: thread (r, cg); dual output
    int r = t >> 4, cg = t & 15;
    float c1[4] = {0.f, 0.f, 0.f, 0.f}, c2[4] = {0.f, 0.f, 0.f, 0.f};
    for (int k0 = 0; k0 < 64; k0 += 4) {
        float4 a = *(const float4*)&Ht[r][k0];
        float av[4] = {a.x, a.y, a.z, a.w};
#pragma unroll
        for (int j = 0; j < 4; ++j) {
            float4 w1 = *(const float4*)&Ws1[k0 + j][cg * 4];
            float4 w2 = *(const float4*)&Ws2[k0 + j][cg * 4];
            c1[0] += av[j] * w1.x; c1[1] += av[j] * w1.y;
            c1[2] += av[j] * w1.z; c1[3] += av[j] * w1.w;
            c2[0] += av[j] * w2.x; c2[1] += av[j] * w2.y;
            c2[2] += av[j] * w2.z; c2[3] += av[j] * w2.w;
        }
    }
    int gr = r0 + r;
    if (gr < N) {
        float2 o1, o2;
        *(__half2*)&o1.x = __floats2half2_rn(c1[0], c1[1]);
        *(__half2*)&o1.y = __floats2half2_rn(c1[2], c1[3]);
        *(__half2*)&o2.x = __floats2half2_rn(c2[0], c2[1]);
        *(__half2*)&o2.y = __floats2half2_rn(c2[2], c2[3]);
        ((float2*)(Ah + (size_t)gr * D))[cg] = o1;
        ((float2*)(Bm + (size_t)gr * D))[cg] = o2;
    }
}

// --- kernel 2: h2 = relu(agg(Ah)/deg + B);  Ch = h2@Wg1 ---

__global__ __launch_bounds__(1024) void sage_gemm2_kernel(
    const int* __restrict__ rowbeg, const int* __restrict__ rowend,
    const int* __restrict__ col,
    const __half* __restrict__ Ah, const __half* __restrict__ Bm,
    const float* __restrict__ Wg1,
    __half* __restrict__ h2, __half* __restrict__ Ch, int N)
{
    __shared__ float Ht[64][68];     // 17.4 KB
    __shared__ float Ws1[64][64];    // 16 KB
    int t = threadIdx.x;
    ((float4*)&Ws1[0][0])[t] = ((const float4*)Wg1)[t];

    int w = t >> 6, lane = t & 63;
    int grp = lane >> 4, li = lane & 15;
    int r0 = blockIdx.x * 64;

#pragma unroll
    for (int i = 0; i < 4; ++i) {
        int nt = w * 4 + i;
        int v = r0 + nt;
        if (v < N) {
            int beg = rowbeg[v], end = rowend[v];
            float a0 = 0.f, a1 = 0.f, a2 = 0.f, a3 = 0.f;
            for (int e0 = beg; e0 < end; e0 += 32) {
#pragma unroll
                for (int j = 0; j < 8; ++j) {
                    int e = e0 + 4 * j + grp;
                    float m = (e < end) ? 1.f : 0.f;
                    int ec = (e < end) ? e : (end - 1);
                    int u = col[ec] & 0xFFFF;
                    float2 r = *((const float2*)(Ah + (size_t)u * D) + li);
                    float2 f01 = __half22float2(*(const __half2*)&r.x);
                    float2 f23 = __half22float2(*(const __half2*)&r.y);
                    a0 += m * f01.x; a1 += m * f01.y; a2 += m * f23.x; a3 += m * f23.y;
                }
            }
            a0 += __shfl_xor(a0, 16); a0 += __shfl_xor(a0, 32);
            a1 += __shfl_xor(a1, 16); a1 += __shfl_xor(a1, 32);
            a2 += __shfl_xor(a2, 16); a2 += __shfl_xor(a2, 32);
            a3 += __shfl_xor(a3, 16); a3 += __shfl_xor(a3, 32);
            if (grp == 0) {
                float inv = 1.f / fmaxf((float)(end - beg), 1.f);
                float2 br = *((const float2*)(Bm + (size_t)v * D) + li);
                float2 b01 = __half22float2(*(const __half2*)&br.x);
                float2 b23 = __half22float2(*(const __half2*)&br.y);
                float h0 = fmaxf(a0 * inv + b01.x, 0.f);
                float h1v = fmaxf(a1 * inv + b01.y, 0.f);
                float h2v = fmaxf(a2 * inv + b23.x, 0.f);
                float h3v = fmaxf(a3 * inv + b23.y, 0.f);
                *(float4*)&Ht[nt][li * 4] = make_float4(h0, h1v, h2v, h3v);
                float2 oh;
                *(__half2*)&oh.x = __floats2half2_rn(h0, h1v);
                *(__half2*)&oh.y = __floats2half2_rn(h2v, h3v);
                ((float2*)(h2 + (size_t)v * D))[li] = oh;
            }
        } else if (grp == 0) {
            *(float4*)&Ht[nt][li * 4] = make_float4(0.f, 0.f, 0.f, 0.f);
        }
    }
    __syncthreads();

    int r = t >> 4, cg = t & 15;
    float c1[4] = {0.f, 0.f, 0.f, 0.f};
    for (int k0 = 0; k0 < 64; k0 += 4) {
        float4 a = *(const float4*)&Ht[r][k0];
        float av[4] = {a.x, a.y, a.z, a.w};
#pragma unroll
        for (int j = 0; j < 4; ++j) {
            float4 w1 = *(const float4*)&Ws1[k0 + j][cg * 4];
            c1[0] += av[j] * w1.x; c1[1] += av[j] * w1.y;
            c1[2] += av[j] * w1.z; c1[3] += av[j] * w1.w;
        }
    }
    int gr = r0 + r;
    if (gr < N) {
        float2 o1;
        *(__half2*)&o1.x = __floats2half2_rn(c1[0], c1[1]);
        *(__half2*)&o1.y = __floats2half2_rn(c1[2], c1[3]);
        ((float2*)(Ch + (size_t)gr * D))[cg] = o1;
    }
}

// --- kernel 3: t = relu(Ch[v] + agg(Ch) + b1);  h3 = relu(t@Wg2 + b2) ---

__global__ __launch_bounds__(1024) void gin_gemm3_kernel(
    const int* __restrict__ rowbeg, const int* __restrict__ rowend,
    const int* __restrict__ col,
    const __half* __restrict__ Ch,
    const float* __restrict__ b1,
    const float* __restrict__ Wg2, const float* __restrict__ b2,
    __half* __restrict__ h3, int N)
{
    __shared__ float Ht[64][68];     // 17.4 KB
    __shared__ float Ws1[64][64];    // 16 KB
    int t = threadIdx.x;
    ((float4*)&Ws1[0][0])[t] = ((const float4*)Wg2)[t];

    int w = t >> 6, lane = t & 63;
    int grp = lane >> 4, li = lane & 15;
    int r0 = blockIdx.x * 64;

#pragma unroll
    for (int i = 0; i < 4; ++i) {
        int nt = w * 4 + i;
        int v = r0 + nt;
        if (v < N) {
            int beg = rowbeg[v], end = rowend[v];
            float a0 = 0.f, a1 = 0.f, a2 = 0.f, a3 = 0.f;
            for (int e0 = beg; e0 < end; e0 += 32) {
#pragma unroll
                for (int j = 0; j < 8; ++j) {
                    int e = e0 + 4 * j + grp;
                    float m = (e < end) ? 1.f : 0.f;
                    int ec = (e < end) ? e : (end - 1);
                    int u = col[ec] & 0xFFFF;
                    float2 r = *((const float2*)(Ch + (size_t)u * D) + li);
                    float2 f01 = __half22float2(*(const __half2*)&r.x);
                    float2 f23 = __half22float2(*(const __half2*)&r.y);
                    a0 += m * f01.x; a1 += m * f01.y; a2 += m * f23.x; a3 += m * f23.y;
                }
            }
            a0 += __shfl_xor(a0, 16); a0 += __shfl_xor(a0, 32);
            a1 += __shfl_xor(a1, 16); a1 += __shfl_xor(a1, 32);
            a2 += __shfl_xor(a2, 16); a2 += __shfl_xor(a2, 32);
            a3 += __shfl_xor(a3, 16); a3 += __shfl_xor(a3, 32);
            if (grp == 0) {
                float2 rs = *((const float2*)(Ch + (size_t)v * D) + li);   // self term
                float2 s01 = __half22float2(*(const __half2*)&rs.x);
                float2 s23 = __half22float2(*(const __half2*)&rs.y);
                float4 bb = ((const float4*)b1)[li];
                float t0 = fmaxf(s01.x + a0 + bb.x, 0.f);
                float t1 = fmaxf(s01.y + a1 + bb.y, 0.f);
                float t2 = fmaxf(s23.x + a2 + bb.z, 0.f);
                float t3 = fmaxf(s23.y + a3 + bb.w, 0.f);
                *(float4*)&Ht[nt][li * 4] = make_float4(t0, t1, t2, t3);
            }
        } else if (grp == 0) {
            *(float4*)&Ht[nt][li * 4] = make_float4(0.f, 0.f, 0.f, 0.f);
        }
    }
    __syncthreads();

    int r = t >> 4, cg = t & 15;
    float c1[4] = {0.f, 0.f, 0.f, 0.f};
    for (int k0 = 0; k0 < 64; k0 += 4) {
        float4 a = *(const float4*)&Ht[r][k0];
        float av[4] = {a.x, a.y, a.z, a.w};
#pragma unroll
        for (int j = 0; j < 4; ++j) {
            float4 w1 = *(const float4*)&Ws1[k0 + j][cg * 4];
            c1[0] += av[j] * w1.x; c1[1] += av[j] * w1.y;
            c1[2] += av[j] * w1.z; c1[3] += av[j] * w1.w;
        }
    }
    int gr = r0 + r;
    if (gr < N) {
        float4 bv = ((const float4*)b2)[cg];
        float2 o1;
        *(__half2*)&o1.x = __floats2half2_rn(fmaxf(c1[0] + bv.x, 0.f),
                                             fmaxf(c1[1] + bv.y, 0.f));
        *(__half2*)&o1.y = __floats2half2_rn(fmaxf(c1[2] + bv.z, 0.f),
                                             fmaxf(c1[3] + bv.w, 0.f));
        ((float2*)(h3 + (size_t)gr * D))[cg] = o1;
    }
}

// ===== pooling: 16 waves/graph, half2 reads, row-parity split + LDS tree reduce =====

__global__ __launch_bounds__(1024) void pool_final_kernel(
    const __half* __restrict__ h1, const __half* __restrict__ h2,
    const __half* __restrict__ h3,
    const int* __restrict__ batch, int N,
    const float* __restrict__ W1, const float* __restrict__ W2,
    const float* __restrict__ W3, float* __restrict__ out, int G) {
    __shared__ float r1[16][64];
    __shared__ float r2[16][64];
    __shared__ float r3[16][64];
    int g = blockIdx.x;
    int tid = threadIdx.x;
    int w = tid >> 6, lane = tid & 63;
    int half = lane >> 5, lc = lane & 31;   // lane covers cols 2lc,2lc+1 of row-parity `half`

    int lo = 0, hi = N;
    while (lo < hi) { int mid = (lo + hi) >> 1; if (batch[mid] < g) lo = mid + 1; else hi = mid; }
    int beg = lo;
    hi = N;
    while (lo < hi) { int mid = (lo + hi) >> 1; if (batch[mid] < g + 1) lo = mid + 1; else hi = mid; }
    int end = lo;

    float s1x = 0.f, s1y = 0.f, s2x = 0.f, s2y = 0.f, s3x = 0.f, s3y = 0.f;
    for (int v = beg + 2 * w + half; v < end; v += 32) {
        size_t ro = (size_t)v * D;
        float2 f1 = __half22float2(((const __half2*)(h1 + ro))[lc]);
        float2 f2 = __half22float2(((const __half2*)(h2 + ro))[lc]);
        float2 f3 = __half22float2(((const __half2*)(h3 + ro))[lc]);
        s1x += f1.x; s1y += f1.y;
        s2x += f2.x; s2y += f2.y;
        s3x += f3.x; s3y += f3.y;
    }
    // combine row parities (lane ^ 32 holds the other parity, same columns)
    s1x += __shfl_xor(s1x, 32); s1y += __shfl_xor(s1y, 32);
    s2x += __shfl_xor(s2x, 32); s2y += __shfl_xor(s2y, 32);
    s3x += __shfl_xor(s3x, 32); s3y += __shfl_xor(s3y, 32);
    if (half == 0) {
        ((float2*)r1[w])[lc] = make_float2(s1x, s1y);
        ((float2*)r2[w])[lc] = make_float2(s2x, s2y);
        ((float2*)r3[w])[lc] = make_float2(s3x, s3y);
    }
    __syncthreads();
#pragma unroll
    for (int stride = 8; stride >= 1; stride >>= 1) {
        if (w < stride) {
            r1[w][lane] += r1[w + stride][lane];
            r2[w][lane] += r2[w + stride][lane];
            r3[w][lane] += r3[w + stride][lane];
        }
        __syncthreads();
    }
    if (w == 0) {
        float inv = 1.f / fmaxf((float)(end - beg), 1.f);
        float p1 = r1[0][lane] * inv, p2 = r2[0][lane] * inv, p3 = r3[0][lane] * inv;
        float acc = 0.f;
#pragma unroll
        for (int k = 0; k < D; ++k) {
            acc += __shfl(p1, k) * W1[k * D + lane]
                 + __shfl(p2, k) * W2[k * D + lane]
                 + __shfl(p3, k) * W3[k * D + lane];
        }
        out[(size_t)g * D + lane] = fmaxf(acc, 0.f);
    }
}

// ================= launch =================

static inline size_t align256(size_t x) { return (x + 255) & ~(size_t)255; }

extern "C" void kernel_launch(void* const* d_in, const int* in_sizes, int n_in,
                              void* d_out, int out_size, void* d_ws, size_t ws_size,
                              hipStream_t stream) {
    const int* x      = (const int*)d_in[0];
    const int* ei     = (const int*)d_in[1];
    const int* batch  = (const int*)d_in[2];
    const float* emb  = (const float*)d_in[3];
    const float* Wgcn = (const float*)d_in[4];
    const float* Wsl  = (const float*)d_in[5];
    const float* Wsr  = (const float*)d_in[6];
    const float* Wg1  = (const float*)d_in[7];
    const float* bg1  = (const float*)d_in[8];
    const float* Wg2  = (const float*)d_in[9];
    const float* bg2  = (const float*)d_in[10];
    const float* Wp1  = (const float*)d_in[11];
    const float* Wp2  = (const float*)d_in[12];
    const float* Wp3  = (const float*)d_in[13];
    float* out = (float*)d_out;

    const int N = in_sizes[0];
    const int E = in_sizes[1] / 2;
    const int V = in_sizes[3] / D;
    const int G = out_size / D;
    const int* src = ei;
    const int* dst = ei + E;
    const int NBUCK = (N + 255) >> 8;

    // workspace layout
    char* base = (char*)d_ws;
    size_t off = 0;
    float* embW       = (float*)(base + off); off = align256(off + (size_t)V * D * 4);
    int* bucketFill   = (int*)(base + off);   off = align256(off + 256 * 4);
    int* rowbeg       = (int*)(base + off);   off = align256(off + (size_t)N * 4);
    int* rowend       = (int*)(base + off);   off = align256(off + (size_t)N * 4);
    int* ebuf         = (int*)(base + off);   off = align256(off + (size_t)NBUCK * ECAP * 4);
    int* col          = (int*)(base + off);   off = align256(off + (size_t)NBUCK * ECAP * 4);
    __half* h1        = (__half*)(base + off); off = align256(off + (size_t)N * D * 2);
    __half* h2        = (__half*)(base + off); off = align256(off + (size_t)N * D * 2);
    __half* h3        = (__half*)(base + off); off = align256(off + (size_t)N * D * 2);
    __half* Ah        = (__half*)(base + off); off = align256(off + (size_t)N * D * 2);
    __half* B         = (__half*)(base + off); off = align256(off + (size_t)N * D * 2);
    __half* Ch        = (__half*)(base + off); off = align256(off + (size_t)N * D * 2);
    (void)ws_size;

    hipMemsetAsync(bucketFill, 0, 256 * 4, stream);

    // fused: embW = emb @ Wgcn (blocks [0,NG)) + padded-bucket edge scatter (rest)
    const int NG = (V + 63) / 64;
    const int NTILE = (E + K3E - 1) / K3E;
    embw_scatter_kernel<<<NG + NTILE, 256, 0, stream>>>(emb, V, Wgcn, embW, NG,
                                                        src, dst, x, bucketFill, ebuf, E);

    // CSR build (per-bucket exact)
    csr_build_kernel<<<NBUCK, 1024, 0, stream>>>(ebuf, bucketFill, rowbeg, rowend, col, N);

    // fused gather+GEMM chain (64 nodes/block: 16 waves x 4 nodes/wave gather)
    int nb64 = (N + 63) / 64;
    gcn_gemm1_kernel<<<nb64, 1024, 0, stream>>>(rowbeg, rowend, col, embW,
                                                Wsl, Wsr, h1, Ah, B, N);
    sage_gemm2_kernel<<<nb64, 1024, 0, stream>>>(rowbeg, rowend, col, Ah, B,
                                                 Wg1, h2, Ch, N);
    gin_gemm3_kernel<<<nb64, 1024, 0, stream>>>(rowbeg, rowend, col, Ch,
                                                bg1, Wg2, bg2, h3, N);

    // pooling (16 waves/graph, half2 reads, LDS reduce)
    pool_final_kernel<<<G, 1024, 0, stream>>>(h1, h2, h3, batch, N, Wp1, Wp2, Wp3, out, G);
}